// Round 2
// baseline (7447.156 us; speedup 1.0000x reference)
//
#include <hip/hip_runtime.h>
#include <hip/hip_bf16.h>
#include <cstdint>
#include <cstddef>

// Model_69647189672235: GRU encoder-decoder w/ attention pooling.
// B=256 T=256 D=72 HID=512 H=1024, to_predict=10 (hardcoded; scalar input ignored).
// R2: workspace cut 276MB -> ~199MB (chunked par2lat + chunked attention-score path,
// union scratch); fp32 master h/hs for accuracy. Theory: ws_size ~= 256MiB and the
// R1 overflow guard silently returned (stub-identical absmax proved nothing ran).

using bf16 = __hip_bfloat16;
typedef __attribute__((ext_vector_type(8))) short short8;
typedef __attribute__((ext_vector_type(4))) float floatx4;

#define B_    256
#define T_    256
#define D_    72
#define DP_   96      // D padded to mult of 32 for BK=32
#define HID_  512
#define H_    1024
#define H3_   3072
#define NPRED 10
#define CHUNK 16      // encoder timesteps per xp GEMM
#define RA    8192    // rows per slab in chunked full-size GEMMs

__device__ __forceinline__ float b2f(bf16 v){ return __bfloat162float(v); }
__device__ __forceinline__ bf16  f2b(float v){ return __float2bfloat16(v); }

__device__ __forceinline__ void async_ld16(const bf16* g, bf16* l) {
  __builtin_amdgcn_global_load_lds(
      (const __attribute__((address_space(1))) unsigned int*)g,
      (__attribute__((address_space(3))) unsigned int*)l,
      16, 0, 0);
}

enum { EPI_F32 = 0, EPI_BF16 = 1, EPI_BF16_RELU = 2, EPI_BF16_RELU_PERM = 3 };

// C = epi(A @ B^T + bias). A:[M,K] bf16 row-major, B:[N,K] bf16 row-major (torch layout).
// M % BM == 0, N % BN == 0, K % 32 == 0. ldc == N.
// EPI_BF16_RELU_PERM: global row g=row_off+gm (g = b*256+t, b-major) is written to
// row t*256+b of Cout (b-major -> t-major permute), Cout full-size.
template<int BM, int BN, int WM, int WN, int EPI>
__global__ __launch_bounds__(256, 2) void gemm_bt(
    const bf16* __restrict__ A, const bf16* __restrict__ B,
    const float* __restrict__ bias, void* __restrict__ Cout,
    int M, int N, int K, int row_off)
{
  constexpr int BK = 32;
  constexpr int NWN = BN / WN;
  constexpr int MT = WM / 16, NT = WN / 16;
  constexpr int ASEG = BM * 4;            // 16B segments in A tile
  constexpr int TSEG = (BM + BN) * 4;
  static_assert((BM/WM)*(BN/WN) == 4, "4 waves");
  static_assert(TSEG % 256 == 0, "uniform staging");

  __shared__ __align__(16) bf16 smem[(BM + BN) * BK];
  bf16* As = smem;
  bf16* Bs = smem + BM * BK;

  const int tid  = threadIdx.x;
  const int lane = tid & 63;
  const int wave = tid >> 6;
  const int wm = wave / NWN, wn = wave % NWN;
  const int m0 = blockIdx.y * BM, n0 = blockIdx.x * BN;

  floatx4 acc[MT][NT];
#pragma unroll
  for (int i = 0; i < MT; i++)
#pragma unroll
    for (int j = 0; j < NT; j++)
      acc[i][j] = floatx4{0.f, 0.f, 0.f, 0.f};

  const int krow = (lane >> 4) << 3;
  const int r16  = lane & 15;

  for (int k0 = 0; k0 < K; k0 += BK) {
    __syncthreads();
#pragma unroll
    for (int it = 0; it < TSEG / 256; it++) {
      int s = tid + it * 256;
      const bf16* g;
      if (s < ASEG) {
        int row = s >> 2, kseg = s & 3;
        g = A + (size_t)(m0 + row) * K + k0 + kseg * 8;
      } else {
        int s2 = s - ASEG;
        int row = s2 >> 2, kseg = s2 & 3;
        g = B + (size_t)(n0 + row) * K + k0 + kseg * 8;
      }
      async_ld16(g, smem + (size_t)s * 8);
    }
    __syncthreads();
    short8 af[MT], bfr[NT];
#pragma unroll
    for (int i = 0; i < MT; i++)
      af[i] = *(const short8*)(As + (wm * WM + i * 16 + r16) * BK + krow);
#pragma unroll
    for (int j = 0; j < NT; j++)
      bfr[j] = *(const short8*)(Bs + (wn * WN + j * 16 + r16) * BK + krow);
#pragma unroll
    for (int i = 0; i < MT; i++)
#pragma unroll
      for (int j = 0; j < NT; j++)
        acc[i][j] = __builtin_amdgcn_mfma_f32_16x16x32_bf16(af[i], bfr[j], acc[i][j], 0, 0, 0);
  }

  // epilogue: C/D layout row=(lane>>4)*4+reg, col=lane&15  [m89-verified]
#pragma unroll
  for (int i = 0; i < MT; i++) {
#pragma unroll
    for (int j = 0; j < NT; j++) {
      int gn = n0 + wn * WN + j * 16 + r16;
      float bv = bias ? bias[gn] : 0.f;
#pragma unroll
      for (int r = 0; r < 4; r++) {
        int gm = m0 + wm * WM + i * 16 + ((lane >> 4) << 2) + r;
        float v = acc[i][j][r] + bv;
        if (EPI == EPI_BF16_RELU || EPI == EPI_BF16_RELU_PERM) v = fmaxf(v, 0.f);
        size_t orow;
        if (EPI == EPI_BF16_RELU_PERM) {
          int g = row_off + gm;
          orow = (size_t)(g & 255) * 256 + (size_t)(g >> 8);
        } else {
          orow = (size_t)gm;
        }
        if (EPI == EPI_F32) ((float*)Cout)[orow * (size_t)N + gn] = v;
        else                ((bf16*) Cout)[orow * (size_t)N + gn] = f2b(v);
      }
    }
  }
}

// fp32 -> bf16 with K padding (kout >= kin, pad zeros)
__global__ void convert_pad(const float* __restrict__ in, bf16* __restrict__ out,
                            int rows, int kin, int kout)
{
  size_t idx = (size_t)blockIdx.x * blockDim.x + threadIdx.x;
  if (idx >= (size_t)rows * kout) return;
  int r = idx / kout, c = idx % kout;
  out[idx] = (c < kin) ? f2b(in[(size_t)r * kin + c]) : f2b(0.f);
}

__global__ void h_init(float* __restrict__ h32, bf16* __restrict__ h16)
{
  int idx = blockIdx.x * blockDim.x + threadIdx.x;
  h32[idx] = 0.f;
  h16[idx] = f2b(0.f);
}

// ppad[b][0:72] = bf16(x[b, T-1, :]), rest 0
__global__ void ppad_init(const float* __restrict__ x, bf16* __restrict__ ppad)
{
  int idx = blockIdx.x * blockDim.x + threadIdx.x;  // over B_*DP_
  int b = idx / DP_, c = idx % DP_;
  float v = (c < D_) ? x[((size_t)b * T_ + (T_ - 1)) * D_ + c] : 0.f;
  ppad[idx] = f2b(v);
}

__device__ __forceinline__ float sigm(float v){ return 1.f / (1.f + __expf(-v)); }

// encoder GRU gates. gi: bf16 xp chunk row tt*B+b; gh fp32; h32 fp32 master,
// h16 bf16 GEMM copy; enc_out row t*B+b (aliases latent; rows already consumed).
__global__ void enc_gates(const bf16* __restrict__ xp, int tt,
                          const float* __restrict__ gh,
                          float* __restrict__ h32, bf16* __restrict__ h16,
                          bf16* __restrict__ enc_out, int t)
{
  int idx = blockIdx.x * blockDim.x + threadIdx.x;  // over B_*H_
  int b = idx >> 10, j = idx & (H_ - 1);
  const bf16* gi = xp + ((size_t)tt * B_ + b) * H3_;
  const float* gr = gh + (size_t)b * H3_;
  float ir = b2f(gi[j]), iz = b2f(gi[j + H_]), in_ = b2f(gi[j + 2 * H_]);
  float r = sigm(ir + gr[j]);
  float z = sigm(iz + gr[j + H_]);
  float n = tanhf(in_ + r * gr[j + 2 * H_]);
  float hnew = (1.f - z) * n + z * h32[idx];
  h32[idx] = hnew;
  bf16 hb = f2b(hnew);
  h16[idx] = hb;
  enc_out[((size_t)t * B_ + b) * H_ + j] = hb;
}

// decoder GRUCell gates: gi,gh fp32; hs32 fp32 master, hs16 bf16 copy
__global__ void dec_gates(const float* __restrict__ gi, const float* __restrict__ gh,
                          float* __restrict__ hs32, bf16* __restrict__ hs16)
{
  int idx = blockIdx.x * blockDim.x + threadIdx.x;
  int b = idx >> 10, j = idx & (H_ - 1);
  const float* gir = gi + (size_t)b * H3_;
  const float* ghr = gh + (size_t)b * H3_;
  float r = sigm(gir[j] + ghr[j]);
  float z = sigm(gir[j + H_] + ghr[j + H_]);
  float n = tanhf(gir[j + 2 * H_] + r * ghr[j + 2 * H_]);
  float hnew = (1.f - z) * n + z * hs32[idx];
  hs32[idx] = hnew;
  hs16[idx] = f2b(hnew);
}

// logits[r] = dot(ls1[r,:512], l2s_w2) + b2 ; one wave per row
__global__ void logits_mv(const bf16* __restrict__ ls1, const float* __restrict__ w2,
                          const float* __restrict__ b2, float* __restrict__ logits)
{
  int gw   = (blockIdx.x * blockDim.x + threadIdx.x) >> 6;
  int lane = threadIdx.x & 63;
  const bf16* row = ls1 + (size_t)gw * HID_;
  float s = 0.f;
#pragma unroll
  for (int k = lane; k < HID_; k += 64) s += b2f(row[k]) * w2[k];
#pragma unroll
  for (int off = 32; off > 0; off >>= 1) s += __shfl_down(s, off, 64);
  if (lane == 0) logits[gw] = s + b2[0];
}

// per-b softmax over t (logits t-major [t*B+b]) then Rep[b] = sum_t w_t * enc_out[t,b,:]
__global__ void attention(const float* __restrict__ logits, const bf16* __restrict__ enc_out,
                          float* __restrict__ rep, float* __restrict__ hs32,
                          bf16* __restrict__ hs16)
{
  int b = blockIdx.x, t = threadIdx.x;
  __shared__ float w[T_];
  __shared__ float red[T_];
  float lg = logits[(size_t)t * B_ + b];
  red[t] = lg; __syncthreads();
  for (int s = 128; s > 0; s >>= 1) { if (t < s) red[t] = fmaxf(red[t], red[t + s]); __syncthreads(); }
  float mx = red[0]; __syncthreads();
  float e = __expf(lg - mx);
  w[t] = e; red[t] = e; __syncthreads();
  for (int s = 128; s > 0; s >>= 1) { if (t < s) red[t] += red[t + s]; __syncthreads(); }
  float inv = 1.f / red[0];
  float acc[4] = {0.f, 0.f, 0.f, 0.f};
  for (int tt = 0; tt < T_; tt++) {
    float wt = w[tt] * inv;
    const bf16* row = enc_out + ((size_t)tt * B_ + b) * H_;
#pragma unroll
    for (int i = 0; i < 4; i++) acc[i] += wt * b2f(row[t + i * 256]);
  }
#pragma unroll
  for (int i = 0; i < 4; i++) {
    int j = t + i * 256;
    rep [(size_t)b * H_ + j] = acc[i];
    hs32[(size_t)b * H_ + j] = acc[i];
    hs16[(size_t)b * H_ + j] = f2b(acc[i]);
  }
}

// pred[b][n] = dot(e1[b,:512], l2p_w2[n,:]) + b2[n]; write d_out and feed back ppad
__global__ void pred_k(const bf16* __restrict__ e1, const float* __restrict__ w2,
                       const float* __restrict__ b2, float* __restrict__ out,
                       bf16* __restrict__ ppad, int s)
{
  int b = blockIdx.x, t = threadIdx.x;
  __shared__ float ev[HID_];
  for (int k = t; k < HID_; k += 256) ev[k] = b2f(e1[(size_t)b * HID_ + k]);
  __syncthreads();
  if (t < D_) {
    float acc = b2[t];
    const float* wr = w2 + (size_t)t * HID_;
    for (int k = 0; k < HID_; k++) acc += ev[k] * wr[k];
    out[(size_t)b * (NPRED * D_) + s * D_ + t] = acc;
    ppad[b * DP_ + t] = f2b(acc);
  }
}

extern "C" void kernel_launch(void* const* d_in, const int* in_sizes, int n_in,
                              void* d_out, int out_size, void* d_ws, size_t ws_size,
                              hipStream_t stream)
{
  const float* x       = (const float*)d_in[0];
  const float* p2l_w1  = (const float*)d_in[2];
  const float* p2l_b1  = (const float*)d_in[3];
  const float* p2l_w2  = (const float*)d_in[4];
  const float* p2l_b2  = (const float*)d_in[5];
  const float* enc_wih = (const float*)d_in[6];
  const float* enc_whh = (const float*)d_in[7];
  const float* enc_bih = (const float*)d_in[8];
  const float* enc_bhh = (const float*)d_in[9];
  const float* dec_wih = (const float*)d_in[10];
  const float* dec_whh = (const float*)d_in[11];
  const float* dec_bih = (const float*)d_in[12];
  const float* dec_bhh = (const float*)d_in[13];
  const float* l2p_w1  = (const float*)d_in[14];
  const float* l2p_b1  = (const float*)d_in[15];
  const float* l2p_w2  = (const float*)d_in[16];
  const float* l2p_b2  = (const float*)d_in[17];
  const float* l2s_w1  = (const float*)d_in[18];
  const float* l2s_b1  = (const float*)d_in[19];
  const float* l2s_w2  = (const float*)d_in[20];
  const float* l2s_b2  = (const float*)d_in[21];

  float* out_preds = (float*)d_out;
  float* out_rep   = (float*)d_out + (size_t)B_ * NPRED * D_;

  // ---- workspace carve-up (256B aligned), target < 256 MiB ----
  char* p = (char*)d_ws;
  auto alloc = [&](size_t bytes) -> char* {
    char* r = p; p += (bytes + 255) & ~(size_t)255; return r;
  };
  bf16* w_p2l1 = (bf16*)alloc((size_t)HID_ * DP_ * 2);
  bf16* w_p2l2 = (bf16*)alloc((size_t)H_ * HID_ * 2);
  bf16* w_ewih = (bf16*)alloc((size_t)H3_ * H_ * 2);
  bf16* w_ewhh = (bf16*)alloc((size_t)H3_ * H_ * 2);
  bf16* w_dwih = (bf16*)alloc((size_t)H3_ * H_ * 2);
  bf16* w_dwhh = (bf16*)alloc((size_t)H3_ * H_ * 2);
  bf16* w_l2p1 = (bf16*)alloc((size_t)HID_ * H_ * 2);
  bf16* w_l2s1 = (bf16*)alloc((size_t)HID_ * H_ * 2);
  bf16* latent = (bf16*)alloc((size_t)B_ * T_ * H_ * 2);   // t-major; aliased as enc_out
  // union scratch: phase A/B: xb(12.6M)+tmpc(8.4M); phase C: xpc(25.2M); phase D: lsc(8.4M)
  char* scratch = alloc((size_t)CHUNK * B_ * H3_ * 2);
  bf16* xb   = (bf16*)scratch;                              // [TB, DP]
  bf16* tmpc = (bf16*)(scratch + (size_t)B_ * T_ * DP_ * 2); // [RA, HID]
  bf16* xpc  = (bf16*)scratch;                              // [CHUNK*B, H3]
  bf16* lsc  = (bf16*)scratch;                              // [RA, HID]
  float* ghb  = (float*)alloc((size_t)B_ * H3_ * 4);
  float* gib  = (float*)alloc((size_t)B_ * H3_ * 4);
  float* h32  = (float*)alloc((size_t)B_ * H_ * 4);
  bf16*  h16  = (bf16*) alloc((size_t)B_ * H_ * 2);
  float* hs32 = (float*)alloc((size_t)B_ * H_ * 4);
  bf16*  hs16 = (bf16*) alloc((size_t)B_ * H_ * 2);
  float* logit= (float*)alloc((size_t)B_ * T_ * 4);
  bf16*  d1   = (bf16*) alloc((size_t)B_ * HID_ * 2);
  bf16*  inp  = (bf16*) alloc((size_t)B_ * H_ * 2);
  bf16*  e1   = (bf16*) alloc((size_t)B_ * HID_ * 2);
  bf16*  ppad = (bf16*) alloc((size_t)B_ * DP_ * 2);
  bf16*  enc_out = latent;

  if ((size_t)(p - (char*)d_ws) > ws_size) return;  // ~199 MB needed

  const int TB = B_ * T_;  // 65536

  // ---- weight / input conversions to bf16 (K padded to mult of 32) ----
  auto cgrid = [](size_t n) { return dim3((unsigned)((n + 255) / 256)); };
  convert_pad<<<cgrid((size_t)TB * DP_),   256, 0, stream>>>(x,       xb,     TB,   D_,   DP_);
  convert_pad<<<cgrid((size_t)HID_ * DP_), 256, 0, stream>>>(p2l_w1,  w_p2l1, HID_, D_,   DP_);
  convert_pad<<<cgrid((size_t)H_ * HID_),  256, 0, stream>>>(p2l_w2,  w_p2l2, H_,   HID_, HID_);
  convert_pad<<<cgrid((size_t)H3_ * H_),   256, 0, stream>>>(enc_wih, w_ewih, H3_,  H_,   H_);
  convert_pad<<<cgrid((size_t)H3_ * H_),   256, 0, stream>>>(enc_whh, w_ewhh, H3_,  H_,   H_);
  convert_pad<<<cgrid((size_t)H3_ * H_),   256, 0, stream>>>(dec_wih, w_dwih, H3_,  H_,   H_);
  convert_pad<<<cgrid((size_t)H3_ * H_),   256, 0, stream>>>(dec_whh, w_dwhh, H3_,  H_,   H_);
  convert_pad<<<cgrid((size_t)HID_ * H_),  256, 0, stream>>>(l2p_w1,  w_l2p1, HID_, H_,   H_);
  convert_pad<<<cgrid((size_t)HID_ * H_),  256, 0, stream>>>(l2s_w1,  w_l2s1, HID_, H_,   H_);

  // ---- par2lat(x) in 8192-row slabs: GEMM1 -> tmpc, GEMM2 -> latent (permuted) ----
  for (int rc = 0; rc < TB / RA; rc++) {
    { dim3 g(HID_ / 128, RA / 128);
      gemm_bt<128,128,64,64,EPI_BF16_RELU><<<g, 256, 0, stream>>>(
          xb + (size_t)rc * RA * DP_, w_p2l1, p2l_b1, tmpc, RA, HID_, DP_, 0); }
    { dim3 g(H_ / 128, RA / 128);
      gemm_bt<128,128,64,64,EPI_BF16_RELU_PERM><<<g, 256, 0, stream>>>(
          tmpc, w_p2l2, p2l_b2, latent, RA, H_, HID_, rc * RA); }
  }

  // ---- encoder GRU: chunked xp GEMM + 256 sequential steps ----
  h_init<<<(B_ * H_) / 256, 256, 0, stream>>>(h32, h16);
  for (int tc = 0; tc < T_ / CHUNK; tc++) {
    dim3 g(H3_ / 128, (CHUNK * B_) / 128);
    gemm_bt<128,128,64,64,EPI_BF16><<<g, 256, 0, stream>>>(
        latent + (size_t)tc * CHUNK * B_ * H_, w_ewih, enc_bih, xpc,
        CHUNK * B_, H3_, H_, 0);
    for (int tt = 0; tt < CHUNK; tt++) {
      dim3 gs(H3_ / 128, B_ / 64);
      gemm_bt<64,128,32,64,EPI_F32><<<gs, 256, 0, stream>>>(
          h16, w_ewhh, enc_bhh, ghb, B_, H3_, H_, 0);
      enc_gates<<<(B_ * H_) / 256, 256, 0, stream>>>(
          xpc, tt, ghb, h32, h16, enc_out, tc * CHUNK + tt);
    }
  }

  // ---- attention pooling (chunked score path) -> Rep + hs ----
  for (int rc = 0; rc < TB / RA; rc++) {
    dim3 g(HID_ / 128, RA / 128);
    gemm_bt<128,128,64,64,EPI_BF16_RELU><<<g, 256, 0, stream>>>(
        enc_out + (size_t)rc * RA * H_, w_l2s1, l2s_b1, lsc, RA, HID_, H_, 0);
    logits_mv<<<RA / 4, 256, 0, stream>>>(lsc, l2s_w2, l2s_b2, logit + (size_t)rc * RA);
  }
  attention<<<B_, 256, 0, stream>>>(logit, enc_out, out_rep, hs32, hs16);

  // ---- autoregressive decoder: 10 steps ----
  ppad_init<<<(B_ * DP_) / 256, 256, 0, stream>>>(x, ppad);
  for (int s = 0; s < NPRED; s++) {
    { dim3 g(HID_ / 128, B_ / 64);
      gemm_bt<64,128,32,64,EPI_BF16_RELU><<<g, 256, 0, stream>>>(ppad, w_p2l1, p2l_b1, d1, B_, HID_, DP_, 0); }
    { dim3 g(H_ / 128, B_ / 64);
      gemm_bt<64,128,32,64,EPI_BF16_RELU><<<g, 256, 0, stream>>>(d1, w_p2l2, p2l_b2, inp, B_, H_, HID_, 0); }
    { dim3 g(H3_ / 128, B_ / 64);
      gemm_bt<64,128,32,64,EPI_F32><<<g, 256, 0, stream>>>(inp, w_dwih, dec_bih, gib, B_, H3_, H_, 0); }
    { dim3 g(H3_ / 128, B_ / 64);
      gemm_bt<64,128,32,64,EPI_F32><<<g, 256, 0, stream>>>(hs16, w_dwhh, dec_bhh, ghb, B_, H3_, H_, 0); }
    dec_gates<<<(B_ * H_) / 256, 256, 0, stream>>>(gib, ghb, hs32, hs16);
    { dim3 g(HID_ / 128, B_ / 64);
      gemm_bt<64,128,32,64,EPI_BF16_RELU><<<g, 256, 0, stream>>>(hs16, w_l2p1, l2p_b1, e1, B_, HID_, H_, 0); }
    pred_k<<<B_, 256, 0, stream>>>(e1, l2p_w2, l2p_b2, out_preds, ppad, s);
  }
}